// Round 1
// baseline (246.038 us; speedup 1.0000x reference)
//
#include <hip/hip_runtime.h>

#define NB    65536
#define NT    512
#define SLEN  12
#define BLOCK 256
#define ROWS  8      // rows per block (2 per wave)
#define CHUNKS 32    // chunks per row = lanes per 32-lane row group
#define CLEN  16     // timesteps per chunk

// Affine-scan decomposition, barrier-free version.
// x_t = A x_{t-1} + b_t with constant A. Each lane runs one 16-step chunk
// zero-init (chunk 0 exact). Entering states come from a Kogge-Stone
// inclusive scan over the 32 chunks of a row: all chunk transition matrices
// equal M = A^16, so step d only needs the constant matrix M^(2^d) and a
// __shfl_up — no LDS, no barriers, no serial per-row combine.
// Correction: o_k += u_{k+1} . S with u_j = [1,1]A^j.
__global__ __launch_bounds__(BLOCK) void holtwinters_kernel(
    const float* __restrict__ series,
    const int*   __restrict__ shifts,
    const float* __restrict__ alpha_p,
    const float* __restrict__ beta_p,
    const float* __restrict__ init_season,
    const float* __restrict__ trend0_p,
    float*       __restrict__ out)
{
    __shared__ float  ss[SLEN];
    __shared__ float2 u[CLEN + 1];   // u_j = [1,1] A^j, j=1..16 (all-lane broadcast reads)
    __shared__ float4 Mp[5];         // (m00,m01,m10,m11) of M^(16*2^d), d=0..4

    const int t = threadIdx.x;
    const float alpha  = alpha_p[0];
    const float beta   = beta_p[0];
    const float oma    = 1.0f - alpha;
    const float omb    = 1.0f - beta;
    const float trend0 = trend0_p[0];

    if (t < SLEN) ss[t] = init_season[t];
    if (t == 0) {
        const float a00 = oma, a01 = oma;
        const float a10 = -alpha * beta, a11 = beta * oma + omb;
        float p0 = 1.0f, p1 = 1.0f;               // [1,1] A^0
        for (int j = 1; j <= CLEN; ++j) {         // row-vec * A
            const float q0 = p0 * a00 + p1 * a10;
            const float q1 = p0 * a01 + p1 * a11;
            p0 = q0; p1 = q1;
            u[j] = make_float2(p0, p1);
        }
        float m00 = a00, m01 = a01, m10 = a10, m11 = a11;
        for (int sq = 0; sq < 4; ++sq) {          // A^2, A^4, A^8, A^16
            const float n00 = m00*m00 + m01*m10;
            const float n01 = m00*m01 + m01*m11;
            const float n10 = m10*m00 + m11*m10;
            const float n11 = m10*m01 + m11*m11;
            m00 = n00; m01 = n01; m10 = n10; m11 = n11;
        }
        for (int d = 0; d < 5; ++d) {             // M^16, M^32, M^64, M^128, M^256
            Mp[d] = make_float4(m00, m01, m10, m11);
            const float n00 = m00*m00 + m01*m10;
            const float n01 = m00*m01 + m01*m11;
            const float n10 = m10*m00 + m11*m10;
            const float n11 = m10*m01 + m11*m11;
            m00 = n00; m01 = n01; m10 = n10; m11 = n11;
        }
    }
    __syncthreads();   // the only barrier in the kernel

    const int r     = t >> 5;                 // row within block
    const int c     = t & 31;                 // chunk within row
    const int row   = blockIdx.x * ROWS + r;
    const int shift = shifts[row];
    int sidx = ((c * CLEN - shift) % SLEN + SLEN) % SLEN;

    // Direct per-lane load: 4x float4 at 64B stride. Each 128B line is fully
    // consumed by 2 lanes x 4 back-to-back instructions -> no over-fetch.
    const float* __restrict__ yb = series + (size_t)row * NT + c * CLEN;
    float o[CLEN];
    *(float4*)&o[0]  = *(const float4*)(yb + 0);
    *(float4*)&o[4]  = *(const float4*)(yb + 4);
    *(float4*)&o[8]  = *(const float4*)(yb + 8);
    *(float4*)&o[12] = *(const float4*)(yb + 12);

    // P1: per-lane zero-init chunk run (chunk 0 runs exact), in place in o[].
    float smooth = 0.0f, trend = 0.0f;
    #pragma unroll
    for (int k = 0; k < CLEN; ++k) {
        const float s = ss[sidx];
        sidx = (sidx + 1 == SLEN) ? 0 : sidx + 1;
        const float yy = o[k];
        if (c == 0 && k == 0) {
            smooth = yy;                       // t==0: res0 = y0 + init_trend
            trend  = trend0;
            o[0]   = smooth + trend;
        } else {
            const float st = smooth + trend;
            const float sm = alpha * (yy - s) + oma * st;
            trend  = beta * (sm - smooth) + omb * trend;
            smooth = sm;
            o[k]   = sm + trend + s;
        }
    }

    // P2: Kogge-Stone inclusive affine scan within each 32-lane row group.
    // E_c = sum_{j<=c} M^(c-j) r_j  (r_0 = exact chunk-0 end state).
    float Ex = smooth, Ey = trend;
    #pragma unroll
    for (int d = 0; d < 5; ++d) {
        const float4 m  = Mp[d];
        const int    dd = 1 << d;
        const float gx = __shfl_up(Ex, dd, CHUNKS);
        const float gy = __shfl_up(Ey, dd, CHUNKS);
        if (c >= dd) {
            Ex += m.x * gx + m.y * gy;
            Ey += m.z * gx + m.w * gy;
        }
    }
    // Entering state of chunk c is the exact end state of chunk c-1.
    const float Sx = __shfl_up(Ex, 1, CHUNKS);
    const float Sy = __shfl_up(Ey, 1, CHUNKS);

    // P3: correction (u[k+1] reads are same-address broadcasts -> free).
    if (c != 0) {
        #pragma unroll
        for (int k = 0; k < CLEN; ++k) {
            const float2 uk = u[k + 1];
            o[k] += uk.x * Sx + uk.y * Sy;
        }
    }

    // P4: direct per-lane store, same 64B-strided full-line pattern.
    float* __restrict__ ob = out + (size_t)row * NT + c * CLEN;
    *(float4*)(ob + 0)  = *(float4*)&o[0];
    *(float4*)(ob + 4)  = *(float4*)&o[4];
    *(float4*)(ob + 8)  = *(float4*)&o[8];
    *(float4*)(ob + 12) = *(float4*)&o[12];
}

extern "C" void kernel_launch(void* const* d_in, const int* in_sizes, int n_in,
                              void* d_out, int out_size, void* d_ws, size_t ws_size,
                              hipStream_t stream) {
    // inputs: 0=series(B*T f32), 1=series_shifts(B i32), 2=alpha, 3=beta,
    //         4=gamma(unused), 5=init_season(12 f32), 6=init_trend, 7=n_preds(unused)
    const float* series      = (const float*)d_in[0];
    const int*   shifts      = (const int*)  d_in[1];
    const float* alpha       = (const float*)d_in[2];
    const float* beta        = (const float*)d_in[3];
    const float* init_season = (const float*)d_in[5];
    const float* init_trend  = (const float*)d_in[6];
    float*       out         = (float*)d_out;

    dim3 block(BLOCK);
    dim3 grid(NB / ROWS);
    hipLaunchKernelGGL(holtwinters_kernel, grid, block, 0, stream,
                       series, shifts, alpha, beta, init_season, init_trend, out);
}